// Round 4
// baseline (166.844 us; speedup 1.0000x reference)
//
#include <hip/hip_runtime.h>
#include <hip/hip_bf16.h>
#include <stdint.h>

// Problem: B=2, S=2048, D=512, H=8, DK=64
#define S_LEN 2048
#define D_MOD 512
#define N_H   8
#define D_K   64

typedef short v8s __attribute__((ext_vector_type(8)));
typedef short v4s __attribute__((ext_vector_type(4)));
typedef float v4f __attribute__((ext_vector_type(4)));

__device__ __forceinline__ short f2bf(float f) {        // RNE
  union { float f; unsigned u; } a; a.f = f;
  unsigned u = a.u;
  u += 0x7fffu + ((u >> 16) & 1u);
  return (short)(u >> 16);
}
__device__ __forceinline__ short f2bfh(float f) {       // round-half-up (p>=0)
  union { float f; unsigned u; } a; a.f = f;
  return (short)((a.u + 0x8000u) >> 16);
}
__device__ __forceinline__ float bf2f(short s) {        // exact
  union { unsigned u; float f; } x;
  x.u = ((unsigned)(unsigned short)s) << 16;
  return x.f;
}

__device__ __forceinline__ v4f mfma16(v8s a, v8s b, v4f c) {
  return __builtin_amdgcn_mfma_f32_16x16x32_bf16(a, b, c, 0, 0, 0);
}
__device__ __forceinline__ v4f mfma16x16(v4s a, v4s b, v4f c) {
  return __builtin_amdgcn_mfma_f32_16x16x16bf16_1k(a, b, c, 0, 0, 0);
}

// ---------------------------------------------------------------------------
// proj (R7-proven): z<3 -> C = A @ Wq^T for A in {q,k,v}, fp32 in, inline bf16
// cvt, VGPR-prefetch pipelined. z==3 -> maskpack (bid<256) or Wo->bf16.
// ---------------------------------------------------------------------------
__global__ __launch_bounds__(256) void proj_kernel(
    const float* __restrict__ q, const float* __restrict__ k,
    const float* __restrict__ v, const float* __restrict__ Wq,
    const float* __restrict__ Wo, const int* __restrict__ mask,
    short* __restrict__ QP, short* __restrict__ KP, short* __restrict__ VT,
    short* __restrict__ Wob, unsigned long long* __restrict__ mp)
{
  const int z = blockIdx.z;
  const int tid = threadIdx.x;
  if (z == 3) {
    int bid = blockIdx.x * 8 + blockIdx.y;           // 0..511
    if (bid < 256) {                                  // maskpack
      int id = bid * 256 + tid;                       // 0..65535
      const int4* m4 = (const int4*)(mask + (size_t)id * 64);
      unsigned long long w = 0ull;
#pragma unroll
      for (int j = 0; j < 16; j++) {
        int4 mv = m4[j];
        w |= (unsigned long long)(mv.x != 0) << (j * 4 + 0);
        w |= (unsigned long long)(mv.y != 0) << (j * 4 + 1);
        w |= (unsigned long long)(mv.z != 0) << (j * 4 + 2);
        w |= (unsigned long long)(mv.w != 0) << (j * 4 + 3);
      }
      mp[id] = w;
    } else {                                          // Wo cvt
      unsigned off = (bid - 256) * 256 + tid;         // 0..65535
      float4 x = ((const float4*)Wo)[off];
      v4s p; p.x = f2bf(x.x); p.y = f2bf(x.y); p.z = f2bf(x.z); p.w = f2bf(x.w);
      ((v4s*)Wob)[off] = p;
    }
    return;
  }
  const float* __restrict__ A = (z == 0) ? q : ((z == 1) ? k : v);
  const int m0 = blockIdx.x * 64, n0 = blockIdx.y * 64;
  const int wave = tid >> 6, lane = tid & 63;
  const int quad = lane >> 4, l15 = lane & 15;
  const int wm = wave >> 1, wn = wave & 1;
  __shared__ short As[64][72];
  __shared__ short Bs[64][72];
  v4f acc[2][2];
#pragma unroll
  for (int i = 0; i < 2; i++)
#pragma unroll
    for (int j = 0; j < 2; j++) acc[i][j] = (v4f){0.f, 0.f, 0.f, 0.f};

  float4 a4[4], b4[4];
#pragma unroll
  for (int i = 0; i < 4; i++) {
    int fi = tid + i * 256, r = fi >> 4, c = (fi & 15) << 2;
    a4[i] = *(const float4*)&A[(m0 + r) * 512 + c];
    b4[i] = *(const float4*)&Wq[(n0 + r) * 512 + c];
  }

  for (int kk = 0; kk < 512; kk += 64) {
    __syncthreads();
#pragma unroll
    for (int i = 0; i < 4; i++) {
      int fi = tid + i * 256, r = fi >> 4, c = (fi & 15) << 2;
      v4s ap; ap.x = f2bf(a4[i].x); ap.y = f2bf(a4[i].y); ap.z = f2bf(a4[i].z); ap.w = f2bf(a4[i].w);
      *(v4s*)&As[r][c] = ap;
      v4s bp; bp.x = f2bf(b4[i].x); bp.y = f2bf(b4[i].y); bp.z = f2bf(b4[i].z); bp.w = f2bf(b4[i].w);
      *(v4s*)&Bs[r][c] = bp;
    }
    __syncthreads();
    if (kk + 64 < 512) {
#pragma unroll
      for (int i = 0; i < 4; i++) {
        int fi = tid + i * 256, r = fi >> 4, c = (fi & 15) << 2;
        a4[i] = *(const float4*)&A[(m0 + r) * 512 + kk + 64 + c];
        b4[i] = *(const float4*)&Wq[(n0 + r) * 512 + kk + 64 + c];
      }
    }
#pragma unroll
    for (int ms = 0; ms < 2; ms++)
#pragma unroll
      for (int ns = 0; ns < 2; ns++)
#pragma unroll
        for (int ks = 0; ks < 2; ks++) {
          union { v8s v; v4s h2[2]; } a, bb;
          a.h2[0]  = *(const v4s*)&As[wm * 32 + ms * 16 + l15][ks * 32 + quad * 8];
          a.h2[1]  = *(const v4s*)&As[wm * 32 + ms * 16 + l15][ks * 32 + quad * 8 + 4];
          bb.h2[0] = *(const v4s*)&Bs[wn * 32 + ns * 16 + l15][ks * 32 + quad * 8];
          bb.h2[1] = *(const v4s*)&Bs[wn * 32 + ns * 16 + l15][ks * 32 + quad * 8 + 4];
          acc[ms][ns] = mfma16(a.v, bb.v, acc[ms][ns]);
        }
  }
#pragma unroll
  for (int ms = 0; ms < 2; ms++)
#pragma unroll
    for (int ns = 0; ns < 2; ns++) {
      int mb = m0 + wm * 32 + ms * 16 + quad * 4;
      int n  = n0 + wn * 32 + ns * 16 + l15;
      int bI = mb >> 11, s = mb & 2047, hh = n >> 6, dk = n & 63;
      if (z == 2) {
        v4s pv;
        pv.x = f2bf(acc[ms][ns][0]); pv.y = f2bf(acc[ms][ns][1]);
        pv.z = f2bf(acc[ms][ns][2]); pv.w = f2bf(acc[ms][ns][3]);
        *(v4s*)&VT[((bI * N_H + hh) * D_K + dk) * S_LEN + s] = pv;
      } else {
        short* dst = (z == 0) ? QP : KP;
#pragma unroll
        for (int r = 0; r < 4; r++)
          dst[((bI * N_H + hh) * S_LEN + (s + r)) * D_K + dk] = f2bf(acc[ms][ns][r]);
      }
    }
}

// ---------------------------------------------------------------------------
// Flash attention v9: within-block key-subtile split for full occupancy.
// Block = 512 thr = 8 waves = 2 q-groups (16 rows each) x 4 tp-owners; each
// wave handles ONE 16-key subtile of every 64-key tile. Grid (64,H,B) = 1024
// blocks = 4 blocks/CU = 32 waves/CU (v8 had 8 -> Occupancy 20%). All waves
// share the same double-buffered K/V tiles (32KB/block, 128KB/CU).
// LDS tiles are [64][64] linear + XOR swizzle cs^=((row&7)<<3): V b64 frag
// reads become 2 lanes/bank (free, was ~4-way = bulk of R3's 6.29M conflict
// cycles); K b128 reads stay at the structural uniform-8.
// tp-partials (accX 16f + accL 4f per lane) are combined via a one-time LDS
// exchange (30.7KB, reuses tile space after last barrier); tp0 normalizes
// in-register and writes FINAL bf16 X. Still no global partials / clean
// outproj (v8's win, kept).
// ---------------------------------------------------------------------------
__global__ __launch_bounds__(512, 8) void attn_kernel(
    const short* __restrict__ QP, const short* __restrict__ KP,
    const short* __restrict__ VT, const unsigned long long* __restrict__ MP,
    short* __restrict__ XB)
{
  const int qt = blockIdx.x;                 // 0..63 (32 q-rows each)
  const int h = blockIdx.y, b = blockIdx.z;
  const int tid = threadIdx.x;               // 0..511
  const int wave = tid >> 6, lane = tid & 63;
  const int quad = lane >> 4, l15 = lane & 15;
  const int tp = wave & 3, qg = wave >> 2;   // owned key-subtile, q-group
  const short* Qh = QP + ((b * N_H + h) * S_LEN) * D_K;
  const short* Kh = KP + ((b * N_H + h) * S_LEN) * D_K;
  const short* Vh = VT + ((b * N_H + h) * D_K) * S_LEN;

  __shared__ short SMEM[2][2][64][64];       // [buf][K=0/V=1][row][col] swz

  const int qrow = qt * 32 + qg * 16;        // this wave's 16 q-rows
  const int srow = tid >> 3;                 // staging row 0..63
  const int sc8  = (tid & 7) * 8;            // staging col (shorts)
  const int scw  = sc8 ^ ((srow & 7) << 3);  // swizzled staging col
  const int swz  = (l15 & 7) << 3;           // read-side swizzle term

  v8s aQ[2];
#pragma unroll
  for (int ks = 0; ks < 2; ks++)
    aQ[ks] = *(const v8s*)&Qh[(qrow + l15) * D_K + ks * 32 + quad * 8];

  const float C1 = 0.18033688011112042f;     // 0.125 * log2(e)
  const float C2 = -11.541560327111707f;     // -8 * log2(e)
  const v4s ONES4 = {16256, 16256, 16256, 16256};
  v4f accX[4], accL = (v4f){0.f, 0.f, 0.f, 0.f};
#pragma unroll
  for (int u = 0; u < 4; u++) accX[u] = (v4f){0.f, 0.f, 0.f, 0.f};

  // tile 0: load regs -> write buf0 directly (swizzled)
  v8s kr = *(const v8s*)&Kh[srow * D_K + sc8];
  v8s vr = *(const v8s*)&Vh[srow * S_LEN + sc8];
  *(v8s*)&SMEM[0][0][srow][scw] = kr;
  *(v8s*)&SMEM[0][1][srow][scw] = vr;
  unsigned long long mwc = MP[(qrow + l15) * 32];
  unsigned long long mwn = 0ull;
  __syncthreads();                           // buf0 visible

  for (int kt = 0; kt < 32; kt++) {
    const int cur = kt & 1;
    if (kt + 1 < 32) {                       // prefetch next tile to regs
      const int c1 = (kt + 1) * 64;
      kr = *(const v8s*)&Kh[(c1 + srow) * D_K + sc8];
      vr = *(const v8s*)&Vh[srow * S_LEN + c1 + sc8];
      mwn = MP[(qrow + l15) * 32 + kt + 1];
    }

    // S^T for this wave's 16-key subtile (q=l15, key=tp*16+quad*4+r)
    v8s bK0 = *(const v8s*)&SMEM[cur][0][tp * 16 + l15][(quad * 8) ^ swz];
    v8s bK1 = *(const v8s*)&SMEM[cur][0][tp * 16 + l15][(32 + quad * 8) ^ swz];
    v4f s = mfma16(bK0, aQ[0], (v4f){0.f, 0.f, 0.f, 0.f});
    s = mfma16(bK1, aQ[1], s);
    unsigned mb = (unsigned)(mwc >> (tp * 16 + quad * 4));
    v4s pk;
#pragma unroll
    for (int r = 0; r < 4; r++) {
      float se = ((mb >> r) & 1u) ? s[r] : 0.0f;     // masked: exp2(C2)=e^-8
      float p = __builtin_amdgcn_exp2f(fmaf(se, C1, C2));
      pk[r] = f2bfh(p);
    }

    // X += P @ V (this tp slice only); L += P @ 1
#pragma unroll
    for (int u = 0; u < 4; u++) {
      v4s bV = *(const v4s*)&SMEM[cur][1][u * 16 + l15][(tp * 16 + quad * 4) ^ swz];
      accX[u] = mfma16x16(pk, bV, accX[u]);
    }
    accL = mfma16x16(pk, ONES4, accL);

    if (kt + 1 < 32) {                       // write next buffer
      *(v8s*)&SMEM[cur ^ 1][0][srow][scw] = kr;
      *(v8s*)&SMEM[cur ^ 1][1][srow][scw] = vr;
    }
    __syncthreads();
    mwc = mwn;
  }

  // combine tp-partials via LDS (tile buffers are dead past the last barrier)
  v4f* ex4 = (v4f*)&SMEM[0][0][0][0];        // 6 waves x 64 lanes x 5 v4f
  if (tp != 0) {
    int widx = (((tp - 1) * 2 + qg) * 64 + lane) * 5;
#pragma unroll
    for (int u = 0; u < 4; u++) ex4[widx + u] = accX[u];
    ex4[widx + 4] = accL;
  }
  __syncthreads();
  if (tp == 0) {
#pragma unroll
    for (int t2 = 1; t2 < 4; t2++) {
      int widx = (((t2 - 1) * 2 + qg) * 64 + lane) * 5;
#pragma unroll
      for (int u = 0; u < 4; u++) accX[u] += ex4[widx + u];
      accL += ex4[widx + 4];
    }
    v4f linv;
#pragma unroll
    for (int r = 0; r < 4; r++) linv[r] = 1.0f / accL[r];
#pragma unroll
    for (int u = 0; u < 4; u++)
#pragma unroll
      for (int r = 0; r < 4; r++) {
        int srw = qrow + quad * 4 + r;
        XB[(b * S_LEN + srw) * D_MOD + h * D_K + u * 16 + l15] =
            f2bf(accX[u][r] * linv[r]);
      }
  }
}

// ---------------------------------------------------------------------------
// outproj v2: plain bf16 GEMM out = X @ Wo^T (X already normalized by attn).
// Proj-style VGPR-prefetch pipeline, straight v8s staging (no unpack/sum).
// ---------------------------------------------------------------------------
__global__ __launch_bounds__(256) void outproj_kernel(
    const short* __restrict__ XB, const short* __restrict__ Wob,
    float* __restrict__ out)
{
  const int m0 = blockIdx.x * 64, n0 = blockIdx.y * 64;
  const int tid = threadIdx.x;
  const int wave = tid >> 6, lane = tid & 63;
  const int quad = lane >> 4, l15 = lane & 15;
  const int wm = wave >> 1, wn = wave & 1;
  __shared__ short As[64][72];
  __shared__ short Bs[64][72];

  v4f acc[2][2];
#pragma unroll
  for (int i = 0; i < 2; i++)
#pragma unroll
    for (int j = 0; j < 2; j++) acc[i][j] = (v4f){0.f, 0.f, 0.f, 0.f};

  v8s a8[2], b8[2];
#pragma unroll
  for (int i = 0; i < 2; i++) {
    int fi = tid + i * 256, r = fi >> 3, c = (fi & 7) << 3;
    a8[i] = *(const v8s*)&XB[(m0 + r) * 512 + c];
    b8[i] = *(const v8s*)&Wob[(n0 + r) * 512 + c];
  }

  for (int kk = 0; kk < 512; kk += 64) {
    __syncthreads();
#pragma unroll
    for (int i = 0; i < 2; i++) {
      int fi = tid + i * 256, r = fi >> 3, c = (fi & 7) << 3;
      *(v8s*)&As[r][c] = a8[i];
      *(v8s*)&Bs[r][c] = b8[i];
    }
    __syncthreads();
    if (kk + 64 < 512) {
#pragma unroll
      for (int i = 0; i < 2; i++) {
        int fi = tid + i * 256, r = fi >> 3, c = (fi & 7) << 3;
        a8[i] = *(const v8s*)&XB[(m0 + r) * 512 + kk + 64 + c];
        b8[i] = *(const v8s*)&Wob[(n0 + r) * 512 + kk + 64 + c];
      }
    }
#pragma unroll
    for (int ms = 0; ms < 2; ms++)
#pragma unroll
      for (int ns = 0; ns < 2; ns++)
#pragma unroll
        for (int ks = 0; ks < 2; ks++) {
          union { v8s v; v4s h2[2]; } a, bb;
          a.h2[0]  = *(const v4s*)&As[wm * 32 + ms * 16 + l15][ks * 32 + quad * 8];
          a.h2[1]  = *(const v4s*)&As[wm * 32 + ms * 16 + l15][ks * 32 + quad * 8 + 4];
          bb.h2[0] = *(const v4s*)&Bs[wn * 32 + ns * 16 + l15][ks * 32 + quad * 8];
          bb.h2[1] = *(const v4s*)&Bs[wn * 32 + ns * 16 + l15][ks * 32 + quad * 8 + 4];
          acc[ms][ns] = mfma16(a.v, bb.v, acc[ms][ns]);
        }
  }
#pragma unroll
  for (int ms = 0; ms < 2; ms++)
#pragma unroll
    for (int ns = 0; ns < 2; ns++) {
      int n = n0 + wn * 32 + ns * 16 + l15;
#pragma unroll
      for (int r = 0; r < 4; r++) {
        int m = m0 + wm * 32 + ms * 16 + quad * 4 + r;
        out[m * 512 + n] = acc[ms][ns][r];
      }
    }
}

// ---------------------------------------------------------------------------
extern "C" void kernel_launch(void* const* d_in, const int* in_sizes, int n_in,
                              void* d_out, int out_size, void* d_ws, size_t ws_size,
                              hipStream_t stream) {
  const float* q  = (const float*)d_in[0];
  const float* k  = (const float*)d_in[1];
  const float* v  = (const float*)d_in[2];
  const int* mask = (const int*)d_in[3];
  const float* Wq = (const float*)d_in[4];
  const float* Wo = (const float*)d_in[5];
  float* out = (float*)d_out;
  char* ws = (char*)d_ws;
  // ws: 0:QP 4MB | 4:KP | 8:VT | 16:MP 0.5MB | 16.5:Wob 0.5MB | 17:XB 4MB
  short* QP = (short*)(ws);
  short* KP = (short*)(ws + (4u << 20));
  short* VT = (short*)(ws + (8u << 20));
  unsigned long long* MP = (unsigned long long*)(ws + (16u << 20));
  short* Wob = (short*)(ws + (16u << 20) + (512u << 10));
  short* XB = (short*)(ws + (17u << 20));

  proj_kernel<<<dim3(64, 8, 4), 256, 0, stream>>>(q, k, v, Wq, Wo, mask,
                                                  QP, KP, VT, Wob, MP);
  attn_kernel<<<dim3(64, N_H, 2), 512, 0, stream>>>(QP, KP, VT, MP, XB);
  outproj_kernel<<<dim3(64, 8, 1), 256, 0, stream>>>(XB, Wob, out);
}

// Round 5
// 151.787 us; speedup vs baseline: 1.0992x; 1.0992x over previous
//
#include <hip/hip_runtime.h>
#include <hip/hip_bf16.h>
#include <stdint.h>

// Problem: B=2, S=2048, D=512, H=8, DK=64
#define S_LEN 2048
#define D_MOD 512
#define N_H   8
#define D_K   64

typedef short v8s __attribute__((ext_vector_type(8)));
typedef short v4s __attribute__((ext_vector_type(4)));
typedef float v4f __attribute__((ext_vector_type(4)));

__device__ __forceinline__ short f2bf(float f) {        // RNE
  union { float f; unsigned u; } a; a.f = f;
  unsigned u = a.u;
  u += 0x7fffu + ((u >> 16) & 1u);
  return (short)(u >> 16);
}
__device__ __forceinline__ short f2bfh(float f) {       // round-half-up (p>=0)
  union { float f; unsigned u; } a; a.f = f;
  return (short)((a.u + 0x8000u) >> 16);
}
__device__ __forceinline__ float bf2f(short s) {        // exact
  union { unsigned u; float f; } x;
  x.u = ((unsigned)(unsigned short)s) << 16;
  return x.f;
}

__device__ __forceinline__ v4f mfma16(v8s a, v8s b, v4f c) {
  return __builtin_amdgcn_mfma_f32_16x16x32_bf16(a, b, c, 0, 0, 0);
}
__device__ __forceinline__ v4f mfma16x16(v4s a, v4s b, v4f c) {
  return __builtin_amdgcn_mfma_f32_16x16x16bf16_1k(a, b, c, 0, 0, 0);
}

// ---------------------------------------------------------------------------
// proj (R7-proven): z<3 -> C = A @ Wq^T for A in {q,k,v}, fp32 in, inline bf16
// cvt, VGPR-prefetch pipelined. z==3 -> maskpack (bid<256) or Wo->bf16.
// ---------------------------------------------------------------------------
__global__ __launch_bounds__(256) void proj_kernel(
    const float* __restrict__ q, const float* __restrict__ k,
    const float* __restrict__ v, const float* __restrict__ Wq,
    const float* __restrict__ Wo, const int* __restrict__ mask,
    short* __restrict__ QP, short* __restrict__ KP, short* __restrict__ VT,
    short* __restrict__ Wob, unsigned long long* __restrict__ mp)
{
  const int z = blockIdx.z;
  const int tid = threadIdx.x;
  if (z == 3) {
    int bid = blockIdx.x * 8 + blockIdx.y;           // 0..511
    if (bid < 256) {                                  // maskpack
      int id = bid * 256 + tid;                       // 0..65535
      const int4* m4 = (const int4*)(mask + (size_t)id * 64);
      unsigned long long w = 0ull;
#pragma unroll
      for (int j = 0; j < 16; j++) {
        int4 mv = m4[j];
        w |= (unsigned long long)(mv.x != 0) << (j * 4 + 0);
        w |= (unsigned long long)(mv.y != 0) << (j * 4 + 1);
        w |= (unsigned long long)(mv.z != 0) << (j * 4 + 2);
        w |= (unsigned long long)(mv.w != 0) << (j * 4 + 3);
      }
      mp[id] = w;
    } else {                                          // Wo cvt
      unsigned off = (bid - 256) * 256 + tid;         // 0..65535
      float4 x = ((const float4*)Wo)[off];
      v4s p; p.x = f2bf(x.x); p.y = f2bf(x.y); p.z = f2bf(x.z); p.w = f2bf(x.w);
      ((v4s*)Wob)[off] = p;
    }
    return;
  }
  const float* __restrict__ A = (z == 0) ? q : ((z == 1) ? k : v);
  const int m0 = blockIdx.x * 64, n0 = blockIdx.y * 64;
  const int wave = tid >> 6, lane = tid & 63;
  const int quad = lane >> 4, l15 = lane & 15;
  const int wm = wave >> 1, wn = wave & 1;
  __shared__ short As[64][72];
  __shared__ short Bs[64][72];
  v4f acc[2][2];
#pragma unroll
  for (int i = 0; i < 2; i++)
#pragma unroll
    for (int j = 0; j < 2; j++) acc[i][j] = (v4f){0.f, 0.f, 0.f, 0.f};

  float4 a4[4], b4[4];
#pragma unroll
  for (int i = 0; i < 4; i++) {
    int fi = tid + i * 256, r = fi >> 4, c = (fi & 15) << 2;
    a4[i] = *(const float4*)&A[(m0 + r) * 512 + c];
    b4[i] = *(const float4*)&Wq[(n0 + r) * 512 + c];
  }

  for (int kk = 0; kk < 512; kk += 64) {
    __syncthreads();
#pragma unroll
    for (int i = 0; i < 4; i++) {
      int fi = tid + i * 256, r = fi >> 4, c = (fi & 15) << 2;
      v4s ap; ap.x = f2bf(a4[i].x); ap.y = f2bf(a4[i].y); ap.z = f2bf(a4[i].z); ap.w = f2bf(a4[i].w);
      *(v4s*)&As[r][c] = ap;
      v4s bp; bp.x = f2bf(b4[i].x); bp.y = f2bf(b4[i].y); bp.z = f2bf(b4[i].z); bp.w = f2bf(b4[i].w);
      *(v4s*)&Bs[r][c] = bp;
    }
    __syncthreads();
    if (kk + 64 < 512) {
#pragma unroll
      for (int i = 0; i < 4; i++) {
        int fi = tid + i * 256, r = fi >> 4, c = (fi & 15) << 2;
        a4[i] = *(const float4*)&A[(m0 + r) * 512 + kk + 64 + c];
        b4[i] = *(const float4*)&Wq[(n0 + r) * 512 + kk + 64 + c];
      }
    }
#pragma unroll
    for (int ms = 0; ms < 2; ms++)
#pragma unroll
      for (int ns = 0; ns < 2; ns++)
#pragma unroll
        for (int ks = 0; ks < 2; ks++) {
          union { v8s v; v4s h2[2]; } a, bb;
          a.h2[0]  = *(const v4s*)&As[wm * 32 + ms * 16 + l15][ks * 32 + quad * 8];
          a.h2[1]  = *(const v4s*)&As[wm * 32 + ms * 16 + l15][ks * 32 + quad * 8 + 4];
          bb.h2[0] = *(const v4s*)&Bs[wn * 32 + ns * 16 + l15][ks * 32 + quad * 8];
          bb.h2[1] = *(const v4s*)&Bs[wn * 32 + ns * 16 + l15][ks * 32 + quad * 8 + 4];
          acc[ms][ns] = mfma16(a.v, bb.v, acc[ms][ns]);
        }
  }
#pragma unroll
  for (int ms = 0; ms < 2; ms++)
#pragma unroll
    for (int ns = 0; ns < 2; ns++) {
      int mb = m0 + wm * 32 + ms * 16 + quad * 4;
      int n  = n0 + wn * 32 + ns * 16 + l15;
      int bI = mb >> 11, s = mb & 2047, hh = n >> 6, dk = n & 63;
      if (z == 2) {
        v4s pv;
        pv.x = f2bf(acc[ms][ns][0]); pv.y = f2bf(acc[ms][ns][1]);
        pv.z = f2bf(acc[ms][ns][2]); pv.w = f2bf(acc[ms][ns][3]);
        *(v4s*)&VT[((bI * N_H + hh) * D_K + dk) * S_LEN + s] = pv;
      } else {
        short* dst = (z == 0) ? QP : KP;
#pragma unroll
        for (int r = 0; r < 4; r++)
          dst[((bI * N_H + hh) * S_LEN + (s + r)) * D_K + dk] = f2bf(acc[ms][ns][r]);
      }
    }
}

// ---------------------------------------------------------------------------
// Flash attention v10: v7 geometry (the fastest measured: <41.8us) + v9's
// swizzled LDS + single-barrier double-buffer. One block = 128 q-rows x one
// key-quarter (8 tiles); wave computes ALL 4 key-subtiles per tile ->
// 28 MFMAs per barrier interval (v9 had 7 -> overhead-dominated, 60us).
// Grid (64,H,B) = 1024 blocks = 4/CU = 32 waves/CU. LDS [64][64] + XOR
// swizzle (v9-proven: conflicts -33%). Raw bf16 partials + LP; the combine
// is a separate cheap kernel (NOT fused into outproj: R1's fusion was 8x
// redundant and poisoned the GEMM staging with ~90 VALU ops/K-step).
// ---------------------------------------------------------------------------
__global__ __launch_bounds__(512, 4) void attn_kernel(
    const short* __restrict__ QP, const short* __restrict__ KP,
    const short* __restrict__ VT, const unsigned long long* __restrict__ MP,
    short* __restrict__ XB, float* __restrict__ LP)
{
  const int bx = blockIdx.x;                 // 0..63
  const int qt = bx & 15, qu = bx >> 4;      // q-tile (128 rows), key-quarter
  const int h = blockIdx.y, b = blockIdx.z;
  const int tid = threadIdx.x;               // 0..511
  const int wave = tid >> 6, lane = tid & 63;
  const int quad = lane >> 4, l15 = lane & 15;
  const short* Qh = QP + ((b * N_H + h) * S_LEN) * D_K;
  const short* Kh = KP + ((b * N_H + h) * S_LEN) * D_K;
  const short* Vh = VT + ((b * N_H + h) * D_K) * S_LEN;

  __shared__ short SMEM[2][2][64][64];       // [buf][K=0/V=1][row][col] swz

  const int qrow = qt * 128 + wave * 16;     // this wave's 16 q-rows
  const int srow = tid >> 3;                 // staging row 0..63
  const int sc8  = (tid & 7) * 8;            // staging col (shorts)
  const int scw  = sc8 ^ ((srow & 7) << 3);  // swizzled staging col
  const int swz  = (l15 & 7) << 3;           // read-side swizzle term
  const int ck0  = qu * 512;                 // key-quarter base

  v8s aQ[2];
#pragma unroll
  for (int ks = 0; ks < 2; ks++)
    aQ[ks] = *(const v8s*)&Qh[(qrow + l15) * D_K + ks * 32 + quad * 8];

  const float C1 = 0.18033688011112042f;     // 0.125 * log2(e)
  const float C2 = -11.541560327111707f;     // -8 * log2(e)
  const v4s ONES4 = {16256, 16256, 16256, 16256};
  v4f accX[4], accL = (v4f){0.f, 0.f, 0.f, 0.f};
#pragma unroll
  for (int u = 0; u < 4; u++) accX[u] = (v4f){0.f, 0.f, 0.f, 0.f};

  // tile 0: load regs -> write buf0 directly (swizzled)
  v8s kr = *(const v8s*)&Kh[(ck0 + srow) * D_K + sc8];
  v8s vr = *(const v8s*)&Vh[srow * S_LEN + ck0 + sc8];
  *(v8s*)&SMEM[0][0][srow][scw] = kr;
  *(v8s*)&SMEM[0][1][srow][scw] = vr;
  unsigned long long mwc = MP[(qrow + l15) * 32 + qu * 8];
  unsigned long long mwn = 0ull;
  __syncthreads();                           // buf0 visible

  for (int kt = 0; kt < 8; kt++) {
    const int cur = kt & 1;
    if (kt + 1 < 8) {                        // prefetch next tile to regs
      const int c1 = ck0 + (kt + 1) * 64;
      kr = *(const v8s*)&Kh[(c1 + srow) * D_K + sc8];
      vr = *(const v8s*)&Vh[srow * S_LEN + c1 + sc8];
      mwn = MP[(qrow + l15) * 32 + qu * 8 + kt + 1];
    }

    // S^T per 16-key tile (q=l15, key=tp*16+quad*4+r); exp -> bf16 A-frags
    v4s pa[4];
#pragma unroll
    for (int tp = 0; tp < 4; tp++) {
      v8s bK0 = *(const v8s*)&SMEM[cur][0][tp * 16 + l15][(quad * 8) ^ swz];
      v8s bK1 = *(const v8s*)&SMEM[cur][0][tp * 16 + l15][(32 + quad * 8) ^ swz];
      v4f s = mfma16(bK0, aQ[0], (v4f){0.f, 0.f, 0.f, 0.f});
      s = mfma16(bK1, aQ[1], s);
      unsigned mb = (unsigned)(mwc >> (tp * 16 + quad * 4));
      v4s pk;
#pragma unroll
      for (int r = 0; r < 4; r++) {
        float se = ((mb >> r) & 1u) ? s[r] : 0.0f;   // masked: exp2(C2)=e^-8
        float p = __builtin_amdgcn_exp2f(fmaf(se, C1, C2));
        pk[r] = f2bfh(p);
      }
      pa[tp] = pk;
    }

    // X += P @ V (register P); L += P @ 1 (row sums on MFMA pipe)
#pragma unroll
    for (int u = 0; u < 4; u++) {
      const short* vb_ = &SMEM[cur][1][u * 16 + l15][0];
#pragma unroll
      for (int tp = 0; tp < 4; tp++) {
        v4s bV = *(const v4s*)&vb_[(tp * 16 + quad * 4) ^ swz];
        accX[u] = mfma16x16(pa[tp], bV, accX[u]);
      }
    }
#pragma unroll
    for (int tp = 0; tp < 4; tp++)
      accL = mfma16x16(pa[tp], ONES4, accL);

    if (kt + 1 < 8) {                        // write next buffer
      *(v8s*)&SMEM[cur ^ 1][0][srow][scw] = kr;
      *(v8s*)&SMEM[cur ^ 1][1][srow][scw] = vr;
    }
    __syncthreads();
    mwc = mwn;
  }

  // raw bf16 partials: lane holds X[q=quad*4+r][dk=u*16+l15], l[q=quad*4+r]
  short* xq = XB + (size_t)qu * 2097152u;    // per-quarter plane [B,S,D] bf16
#pragma unroll
  for (int u = 0; u < 4; u++)
#pragma unroll
    for (int r = 0; r < 4; r++) {
      int srw = qrow + quad * 4 + r;
      xq[(b * S_LEN + srw) * D_MOD + h * D_K + u * 16 + l15] = f2bf(accX[u][r]);
    }
  if (l15 == 0) {
#pragma unroll
    for (int r = 0; r < 4; r++) {
      int srw = qrow + quad * 4 + r;
      LP[((qu * 2 + b) * S_LEN + srw) * N_H + h] = accL[r];
    }
  }
}

// ---------------------------------------------------------------------------
// combine: X = (sum_qu XB[qu]) / (sum_qu l). One pass over 16MB+0.5MB read,
// 4MB write — pure BW (~3.5us). Does the combine ONCE (R1's fused version
// redid it 8x inside outproj's staging).
// ---------------------------------------------------------------------------
__global__ __launch_bounds__(256) void combine_kernel(
    const short* __restrict__ XB, const float* __restrict__ LP,
    short* __restrict__ X)
{
  int g = blockIdx.x * 256 + threadIdx.x;    // 0..262143 (v8s groups)
  int d8 = g & 63, sf = g >> 6;              // 64 groups/row, sf 0..4095
  int b = sf >> 11, s = sf & 2047, hh = d8 >> 3;
  size_t base = (size_t)g * 8;

  float l = 0.f;
#pragma unroll
  for (int qu = 0; qu < 4; qu++)
    l += LP[((qu * 2 + b) * S_LEN + s) * N_H + hh];
  float inv = 1.0f / l;

  float acc[8];
#pragma unroll
  for (int j = 0; j < 8; j++) acc[j] = 0.f;
#pragma unroll
  for (int qu = 0; qu < 4; qu++) {
    v8s t = *(const v8s*)(XB + (size_t)qu * 2097152u + base);
#pragma unroll
    for (int j = 0; j < 8; j++) acc[j] += bf2f(t[j]);
  }
  v8s o;
#pragma unroll
  for (int j = 0; j < 8; j++) o[j] = f2bf(acc[j] * inv);
  *(v8s*)(X + base) = o;
}

// ---------------------------------------------------------------------------
// outproj (R4-proven clean): plain bf16 GEMM out = X @ Wo^T.
// ---------------------------------------------------------------------------
__global__ __launch_bounds__(256) void outproj_kernel(
    const short* __restrict__ X, const short* __restrict__ Wob,
    float* __restrict__ out)
{
  const int m0 = blockIdx.x * 64, n0 = blockIdx.y * 64;
  const int tid = threadIdx.x;
  const int wave = tid >> 6, lane = tid & 63;
  const int quad = lane >> 4, l15 = lane & 15;
  const int wm = wave >> 1, wn = wave & 1;
  __shared__ short As[64][72];
  __shared__ short Bs[64][72];

  v4f acc[2][2];
#pragma unroll
  for (int i = 0; i < 2; i++)
#pragma unroll
    for (int j = 0; j < 2; j++) acc[i][j] = (v4f){0.f, 0.f, 0.f, 0.f};

  v8s a8[2], b8[2];
#pragma unroll
  for (int i = 0; i < 2; i++) {
    int fi = tid + i * 256, r = fi >> 3, c = (fi & 7) << 3;
    a8[i] = *(const v8s*)&X[(m0 + r) * 512 + c];
    b8[i] = *(const v8s*)&Wob[(n0 + r) * 512 + c];
  }

  for (int kk = 0; kk < 512; kk += 64) {
    __syncthreads();
#pragma unroll
    for (int i = 0; i < 2; i++) {
      int fi = tid + i * 256, r = fi >> 3, c = (fi & 7) << 3;
      *(v8s*)&As[r][c] = a8[i];
      *(v8s*)&Bs[r][c] = b8[i];
    }
    __syncthreads();
    if (kk + 64 < 512) {
#pragma unroll
      for (int i = 0; i < 2; i++) {
        int fi = tid + i * 256, r = fi >> 3, c = (fi & 7) << 3;
        a8[i] = *(const v8s*)&X[(m0 + r) * 512 + kk + 64 + c];
        b8[i] = *(const v8s*)&Wob[(n0 + r) * 512 + kk + 64 + c];
      }
    }
#pragma unroll
    for (int ms = 0; ms < 2; ms++)
#pragma unroll
      for (int ns = 0; ns < 2; ns++)
#pragma unroll
        for (int ks = 0; ks < 2; ks++) {
          union { v8s v; v4s h2[2]; } a, bb;
          a.h2[0]  = *(const v4s*)&As[wm * 32 + ms * 16 + l15][ks * 32 + quad * 8];
          a.h2[1]  = *(const v4s*)&As[wm * 32 + ms * 16 + l15][ks * 32 + quad * 8 + 4];
          bb.h2[0] = *(const v4s*)&Bs[wn * 32 + ns * 16 + l15][ks * 32 + quad * 8];
          bb.h2[1] = *(const v4s*)&Bs[wn * 32 + ns * 16 + l15][ks * 32 + quad * 8 + 4];
          acc[ms][ns] = mfma16(a.v, bb.v, acc[ms][ns]);
        }
  }
#pragma unroll
  for (int ms = 0; ms < 2; ms++)
#pragma unroll
    for (int ns = 0; ns < 2; ns++) {
      int n = n0 + wn * 32 + ns * 16 + l15;
#pragma unroll
      for (int r = 0; r < 4; r++) {
        int m = m0 + wm * 32 + ms * 16 + quad * 4 + r;
        out[m * 512 + n] = acc[ms][ns][r];
      }
    }
}

// ---------------------------------------------------------------------------
extern "C" void kernel_launch(void* const* d_in, const int* in_sizes, int n_in,
                              void* d_out, int out_size, void* d_ws, size_t ws_size,
                              hipStream_t stream) {
  const float* q  = (const float*)d_in[0];
  const float* k  = (const float*)d_in[1];
  const float* v  = (const float*)d_in[2];
  const int* mask = (const int*)d_in[3];
  const float* Wq = (const float*)d_in[4];
  const float* Wo = (const float*)d_in[5];
  float* out = (float*)d_out;
  char* ws = (char*)d_ws;
  // ws: 0:QP 4MB | 4:KP | 8:VT | 16:MP 0.5MB | 16.5:Wob 0.5MB |
  //     17:XB 16MB (4 partial planes) | 33:LP 0.5MB | 34:X 4MB
  short* QP = (short*)(ws);
  short* KP = (short*)(ws + (4u << 20));
  short* VT = (short*)(ws + (8u << 20));
  unsigned long long* MP = (unsigned long long*)(ws + (16u << 20));
  short* Wob = (short*)(ws + (16u << 20) + (512u << 10));
  short* XB = (short*)(ws + (17u << 20));
  float* LP = (float*)(ws + (33u << 20));
  short* X  = (short*)(ws + (34u << 20));

  proj_kernel<<<dim3(64, 8, 4), 256, 0, stream>>>(q, k, v, Wq, Wo, mask,
                                                  QP, KP, VT, Wob, MP);
  attn_kernel<<<dim3(64, N_H, 2), 512, 0, stream>>>(QP, KP, VT, MP, XB, LP);
  combine_kernel<<<dim3(1024, 1, 1), 256, 0, stream>>>(XB, LP, X);
  outproj_kernel<<<dim3(64, 8, 1), 256, 0, stream>>>(X, Wob, out);
}

// Round 6
// 148.159 us; speedup vs baseline: 1.1261x; 1.0245x over previous
//
#include <hip/hip_runtime.h>
#include <hip/hip_bf16.h>
#include <stdint.h>

// Problem: B=2, S=2048, D=512, H=8, DK=64
#define S_LEN 2048
#define D_MOD 512
#define N_H   8
#define D_K   64

typedef short v8s __attribute__((ext_vector_type(8)));
typedef short v4s __attribute__((ext_vector_type(4)));
typedef float v4f __attribute__((ext_vector_type(4)));

__device__ __forceinline__ short f2bf(float f) {        // RNE
  union { float f; unsigned u; } a; a.f = f;
  unsigned u = a.u;
  u += 0x7fffu + ((u >> 16) & 1u);
  return (short)(u >> 16);
}
__device__ __forceinline__ short f2bfh(float f) {       // round-half-up (p>=0)
  union { float f; unsigned u; } a; a.f = f;
  return (short)((a.u + 0x8000u) >> 16);
}
__device__ __forceinline__ float bf2f(short s) {        // exact
  union { unsigned u; float f; } x;
  x.u = ((unsigned)(unsigned short)s) << 16;
  return x.f;
}
// HW packed f32->bf16 (RNE), 2 values/instr — T12 recipe, gfx950-verified
__device__ __forceinline__ unsigned pk2(float a, float b) {
  unsigned r;
  asm("v_cvt_pk_bf16_f32 %0, %1, %2" : "=v"(r) : "v"(a), "v"(b));
  return r;
}

__device__ __forceinline__ v4f mfma16(v8s a, v8s b, v4f c) {
  return __builtin_amdgcn_mfma_f32_16x16x32_bf16(a, b, c, 0, 0, 0);
}
__device__ __forceinline__ v4f mfma16x16(v4s a, v4s b, v4f c) {
  return __builtin_amdgcn_mfma_f32_16x16x16bf16_1k(a, b, c, 0, 0, 0);
}

// ---------------------------------------------------------------------------
// proj: z<3 -> C = A @ Wq^T for A in {q,k,v}, fp32 in. Staging cvt now uses
// v_cvt_pk_bf16_f32 (16 instrs/K-step/thread vs ~128 manual-RNE VALU ops —
// tests the "proj is staging-VALU-bound" hypothesis). z==3 -> maskpack /
// Wo->bf16 (unchanged).
// ---------------------------------------------------------------------------
__global__ __launch_bounds__(256) void proj_kernel(
    const float* __restrict__ q, const float* __restrict__ k,
    const float* __restrict__ v, const float* __restrict__ Wq,
    const float* __restrict__ Wo, const int* __restrict__ mask,
    short* __restrict__ QP, short* __restrict__ KP, short* __restrict__ VT,
    short* __restrict__ Wob, unsigned long long* __restrict__ mp)
{
  const int z = blockIdx.z;
  const int tid = threadIdx.x;
  if (z == 3) {
    int bid = blockIdx.x * 8 + blockIdx.y;           // 0..511
    if (bid < 256) {                                  // maskpack
      int id = bid * 256 + tid;                       // 0..65535
      const int4* m4 = (const int4*)(mask + (size_t)id * 64);
      unsigned long long w = 0ull;
#pragma unroll
      for (int j = 0; j < 16; j++) {
        int4 mv = m4[j];
        w |= (unsigned long long)(mv.x != 0) << (j * 4 + 0);
        w |= (unsigned long long)(mv.y != 0) << (j * 4 + 1);
        w |= (unsigned long long)(mv.z != 0) << (j * 4 + 2);
        w |= (unsigned long long)(mv.w != 0) << (j * 4 + 3);
      }
      mp[id] = w;
    } else {                                          // Wo cvt
      unsigned off = (bid - 256) * 256 + tid;         // 0..65535
      float4 x = ((const float4*)Wo)[off];
      v4s p; p.x = f2bf(x.x); p.y = f2bf(x.y); p.z = f2bf(x.z); p.w = f2bf(x.w);
      ((v4s*)Wob)[off] = p;
    }
    return;
  }
  const float* __restrict__ A = (z == 0) ? q : ((z == 1) ? k : v);
  const int m0 = blockIdx.x * 64, n0 = blockIdx.y * 64;
  const int wave = tid >> 6, lane = tid & 63;
  const int quad = lane >> 4, l15 = lane & 15;
  const int wm = wave >> 1, wn = wave & 1;
  __shared__ short As[64][72];
  __shared__ short Bs[64][72];
  v4f acc[2][2];
#pragma unroll
  for (int i = 0; i < 2; i++)
#pragma unroll
    for (int j = 0; j < 2; j++) acc[i][j] = (v4f){0.f, 0.f, 0.f, 0.f};

  float4 a4[4], b4[4];
#pragma unroll
  for (int i = 0; i < 4; i++) {
    int fi = tid + i * 256, r = fi >> 4, c = (fi & 15) << 2;
    a4[i] = *(const float4*)&A[(m0 + r) * 512 + c];
    b4[i] = *(const float4*)&Wq[(n0 + r) * 512 + c];
  }

  for (int kk = 0; kk < 512; kk += 64) {
    __syncthreads();
#pragma unroll
    for (int i = 0; i < 4; i++) {
      int fi = tid + i * 256, r = fi >> 4, c = (fi & 15) << 2;
      union { unsigned u[2]; v4s s; } ap, bp;
      ap.u[0] = pk2(a4[i].x, a4[i].y); ap.u[1] = pk2(a4[i].z, a4[i].w);
      bp.u[0] = pk2(b4[i].x, b4[i].y); bp.u[1] = pk2(b4[i].z, b4[i].w);
      *(v4s*)&As[r][c] = ap.s;
      *(v4s*)&Bs[r][c] = bp.s;
    }
    __syncthreads();
    if (kk + 64 < 512) {
#pragma unroll
      for (int i = 0; i < 4; i++) {
        int fi = tid + i * 256, r = fi >> 4, c = (fi & 15) << 2;
        a4[i] = *(const float4*)&A[(m0 + r) * 512 + kk + 64 + c];
        b4[i] = *(const float4*)&Wq[(n0 + r) * 512 + kk + 64 + c];
      }
    }
#pragma unroll
    for (int ms = 0; ms < 2; ms++)
#pragma unroll
      for (int ns = 0; ns < 2; ns++)
#pragma unroll
        for (int ks = 0; ks < 2; ks++) {
          union { v8s v; v4s h2[2]; } a, bb;
          a.h2[0]  = *(const v4s*)&As[wm * 32 + ms * 16 + l15][ks * 32 + quad * 8];
          a.h2[1]  = *(const v4s*)&As[wm * 32 + ms * 16 + l15][ks * 32 + quad * 8 + 4];
          bb.h2[0] = *(const v4s*)&Bs[wn * 32 + ns * 16 + l15][ks * 32 + quad * 8];
          bb.h2[1] = *(const v4s*)&Bs[wn * 32 + ns * 16 + l15][ks * 32 + quad * 8 + 4];
          acc[ms][ns] = mfma16(a.v, bb.v, acc[ms][ns]);
        }
  }
#pragma unroll
  for (int ms = 0; ms < 2; ms++)
#pragma unroll
    for (int ns = 0; ns < 2; ns++) {
      int mb = m0 + wm * 32 + ms * 16 + quad * 4;
      int n  = n0 + wn * 32 + ns * 16 + l15;
      int bI = mb >> 11, s = mb & 2047, hh = n >> 6, dk = n & 63;
      if (z == 2) {
        v4s pv;
        pv.x = f2bf(acc[ms][ns][0]); pv.y = f2bf(acc[ms][ns][1]);
        pv.z = f2bf(acc[ms][ns][2]); pv.w = f2bf(acc[ms][ns][3]);
        *(v4s*)&VT[((bI * N_H + hh) * D_K + dk) * S_LEN + s] = pv;
      } else {
        short* dst = (z == 0) ? QP : KP;
#pragma unroll
        for (int r = 0; r < 4; r++)
          dst[((bI * N_H + hh) * S_LEN + (s + r)) * D_K + dk] = f2bf(acc[ms][ns][r]);
      }
    }
}

// ---------------------------------------------------------------------------
// Flash attention v11: full-S blocks at 2 blocks/CU via KEY-PARITY wave split.
// Block = 512 thr = 8 waves = 4 q-subtiles (16 rows) x 2 key-parity groups;
// group g walks tiles kt === g (mod 2), so the block covers 64 q-rows x all
// 2048 keys. Grid (32,H,B) = 512 blocks = 2/CU = 16 waves/CU (v7-proven
// occupancy; v8's full-S failed at 1 block/CU). Per-wave density stays
// 28 MFMA/barrier (v10-proven). LDS = [pair][parity][K/V][64][64] = 64KB,
// 4-slot double-buffer: compute pair p while reg-prefetched pair p^1 is
// written post-compute -> ONE barrier/iter preserved. XOR swizzle kept.
// End: 2-way in-block LDS combine (21-float stride, conflict-free), then
// in-register normalize -> writes FINAL bf16 X. No partial planes, no LP,
// no combine kernel (-1 dispatch, -12.5MB writes, -16MB reads).
// ---------------------------------------------------------------------------
__global__ __launch_bounds__(512, 4) void attn_kernel(
    const short* __restrict__ QP, const short* __restrict__ KP,
    const short* __restrict__ VT, const unsigned long long* __restrict__ MP,
    short* __restrict__ X)
{
  const int qt = blockIdx.x;                 // 0..31 (64 q-rows each)
  const int h = blockIdx.y, b = blockIdx.z;
  const int tid = threadIdx.x;               // 0..511
  const int wave = tid >> 6, lane = tid & 63;
  const int quad = lane >> 4, l15 = lane & 15;
  const int qw = wave & 3, kg = wave >> 2;   // q-subtile, key-parity group
  const short* Qh = QP + ((b * N_H + h) * S_LEN) * D_K;
  const short* Kh = KP + ((b * N_H + h) * S_LEN) * D_K;
  const short* Vh = VT + ((b * N_H + h) * D_K) * S_LEN;

  __shared__ short SMEM[2][2][2][64][64];    // [pair][parity][K/V][row][col]

  const int qrow = qt * 64 + qw * 16;        // this wave's 16 q-rows
  const int srow = tid >> 3;                 // staging row 0..63
  const int sc8  = (tid & 7) * 8;            // staging col (shorts)
  const int scw  = sc8 ^ ((srow & 7) << 3);  // swizzled staging col
  const int swz  = (l15 & 7) << 3;           // read-side swizzle term

  v8s aQ[2];
#pragma unroll
  for (int ks = 0; ks < 2; ks++)
    aQ[ks] = *(const v8s*)&Qh[(qrow + l15) * D_K + ks * 32 + quad * 8];

  const float C1 = 0.18033688011112042f;     // 0.125 * log2(e)
  const float C2 = -11.541560327111707f;     // -8 * log2(e)
  const v4s ONES4 = {16256, 16256, 16256, 16256};
  v4f accX[4], accL = (v4f){0.f, 0.f, 0.f, 0.f};
#pragma unroll
  for (int u = 0; u < 4; u++) accX[u] = (v4f){0.f, 0.f, 0.f, 0.f};

  // prologue: stage tiles 0 (parity 0) and 1 (parity 1) into pair 0
  v8s kr0 = *(const v8s*)&Kh[srow * D_K + sc8];
  v8s vr0 = *(const v8s*)&Vh[srow * S_LEN + sc8];
  v8s kr1 = *(const v8s*)&Kh[(64 + srow) * D_K + sc8];
  v8s vr1 = *(const v8s*)&Vh[srow * S_LEN + 64 + sc8];
  *(v8s*)&SMEM[0][0][0][srow][scw] = kr0;
  *(v8s*)&SMEM[0][0][1][srow][scw] = vr0;
  *(v8s*)&SMEM[0][1][0][srow][scw] = kr1;
  *(v8s*)&SMEM[0][1][1][srow][scw] = vr1;
  unsigned long long mwc = MP[(qrow + l15) * 32 + kg];
  unsigned long long mwn = 0ull;
  __syncthreads();                           // pair 0 visible

  for (int it = 0; it < 16; it++) {
    const int p = it & 1;
    if (it + 1 < 16) {                       // prefetch next tile-PAIR to regs
      const int c0 = (it + 1) * 128, c1 = c0 + 64;
      kr0 = *(const v8s*)&Kh[(c0 + srow) * D_K + sc8];
      vr0 = *(const v8s*)&Vh[srow * S_LEN + c0 + sc8];
      kr1 = *(const v8s*)&Kh[(c1 + srow) * D_K + sc8];
      vr1 = *(const v8s*)&Vh[srow * S_LEN + c1 + sc8];
      mwn = MP[(qrow + l15) * 32 + 2 * (it + 1) + kg];
    }

    // this wave's tile = 2*it+kg, from SMEM[p][kg]
    // S^T per 16-key subtile (q=l15, key=tp*16+quad*4+r); exp -> bf16 A-frags
    v4s pa[4];
#pragma unroll
    for (int tp = 0; tp < 4; tp++) {
      v8s bK0 = *(const v8s*)&SMEM[p][kg][0][tp * 16 + l15][(quad * 8) ^ swz];
      v8s bK1 = *(const v8s*)&SMEM[p][kg][0][tp * 16 + l15][(32 + quad * 8) ^ swz];
      v4f s = mfma16(bK0, aQ[0], (v4f){0.f, 0.f, 0.f, 0.f});
      s = mfma16(bK1, aQ[1], s);
      unsigned mb = (unsigned)(mwc >> (tp * 16 + quad * 4));
      v4s pk;
#pragma unroll
      for (int r = 0; r < 4; r++) {
        float se = ((mb >> r) & 1u) ? s[r] : 0.0f;   // masked: exp2(C2)=e^-8
        float pr = __builtin_amdgcn_exp2f(fmaf(se, C1, C2));
        pk[r] = f2bfh(pr);
      }
      pa[tp] = pk;
    }

    // X += P @ V (register P); L += P @ 1 (row sums on MFMA pipe)
#pragma unroll
    for (int u = 0; u < 4; u++) {
      const short* vb_ = &SMEM[p][kg][1][u * 16 + l15][0];
#pragma unroll
      for (int tp = 0; tp < 4; tp++) {
        v4s bV = *(const v4s*)&vb_[(tp * 16 + quad * 4) ^ swz];
        accX[u] = mfma16x16(pa[tp], bV, accX[u]);
      }
    }
#pragma unroll
    for (int tp = 0; tp < 4; tp++)
      accL = mfma16x16(pa[tp], ONES4, accL);

    if (it + 1 < 16) {                       // write next pair (p^1 was last
      *(v8s*)&SMEM[p ^ 1][0][0][srow][scw] = kr0;   // read in it-1, fenced)
      *(v8s*)&SMEM[p ^ 1][0][1][srow][scw] = vr0;
      *(v8s*)&SMEM[p ^ 1][1][0][srow][scw] = kr1;
      *(v8s*)&SMEM[p ^ 1][1][1][srow][scw] = vr1;
    }
    __syncthreads();
    mwc = mwn;
  }

  // 2-way combine across key-parity groups via LDS (tile bufs dead), then
  // normalize in-register and write FINAL bf16 X.
  float* ex = (float*)&SMEM[0][0][0][0][0];  // 4 waves x 64 lanes x 21 floats
  const int xi = (qw * 64 + lane) * 21;      // stride 21: conflict-free
  if (kg == 1) {
#pragma unroll
    for (int u = 0; u < 4; u++)
#pragma unroll
      for (int r = 0; r < 4; r++) ex[xi + u * 4 + r] = accX[u][r];
#pragma unroll
    for (int r = 0; r < 4; r++) ex[xi + 16 + r] = accL[r];
  }
  __syncthreads();
  if (kg == 0) {
#pragma unroll
    for (int u = 0; u < 4; u++)
#pragma unroll
      for (int r = 0; r < 4; r++) accX[u][r] += ex[xi + u * 4 + r];
#pragma unroll
    for (int r = 0; r < 4; r++) accL[r] += ex[xi + 16 + r];
    v4f linv;
#pragma unroll
    for (int r = 0; r < 4; r++) linv[r] = 1.0f / accL[r];
#pragma unroll
    for (int u = 0; u < 4; u++)
#pragma unroll
      for (int r = 0; r < 4; r++) {
        int srw = qrow + quad * 4 + r;
        X[(b * S_LEN + srw) * D_MOD + h * D_K + u * 16 + l15] =
            f2bf(accX[u][r] * linv[r]);
      }
  }
}

// ---------------------------------------------------------------------------
// outproj (R4-proven clean): plain bf16 GEMM out = X @ Wo^T.
// ---------------------------------------------------------------------------
__global__ __launch_bounds__(256) void outproj_kernel(
    const short* __restrict__ X, const short* __restrict__ Wob,
    float* __restrict__ out)
{
  const int m0 = blockIdx.x * 64, n0 = blockIdx.y * 64;
  const int tid = threadIdx.x;
  const int wave = tid >> 6, lane = tid & 63;
  const int quad = lane >> 4, l15 = lane & 15;
  const int wm = wave >> 1, wn = wave & 1;
  __shared__ short As[64][72];
  __shared__ short Bs[64][72];

  v4f acc[2][2];
#pragma unroll
  for (int i = 0; i < 2; i++)
#pragma unroll
    for (int j = 0; j < 2; j++) acc[i][j] = (v4f){0.f, 0.f, 0.f, 0.f};

  v8s a8[2], b8[2];
#pragma unroll
  for (int i = 0; i < 2; i++) {
    int fi = tid + i * 256, r = fi >> 3, c = (fi & 7) << 3;
    a8[i] = *(const v8s*)&X[(m0 + r) * 512 + c];
    b8[i] = *(const v8s*)&Wob[(n0 + r) * 512 + c];
  }

  for (int kk = 0; kk < 512; kk += 64) {
    __syncthreads();
#pragma unroll
    for (int i = 0; i < 2; i++) {
      int fi = tid + i * 256, r = fi >> 3, c = (fi & 7) << 3;
      *(v8s*)&As[r][c] = a8[i];
      *(v8s*)&Bs[r][c] = b8[i];
    }
    __syncthreads();
    if (kk + 64 < 512) {
#pragma unroll
      for (int i = 0; i < 2; i++) {
        int fi = tid + i * 256, r = fi >> 3, c = (fi & 7) << 3;
        a8[i] = *(const v8s*)&X[(m0 + r) * 512 + kk + 64 + c];
        b8[i] = *(const v8s*)&Wob[(n0 + r) * 512 + kk + 64 + c];
      }
    }
#pragma unroll
    for (int ms = 0; ms < 2; ms++)
#pragma unroll
      for (int ns = 0; ns < 2; ns++)
#pragma unroll
        for (int ks = 0; ks < 2; ks++) {
          union { v8s v; v4s h2[2]; } a, bb;
          a.h2[0]  = *(const v4s*)&As[wm * 32 + ms * 16 + l15][ks * 32 + quad * 8];
          a.h2[1]  = *(const v4s*)&As[wm * 32 + ms * 16 + l15][ks * 32 + quad * 8 + 4];
          bb.h2[0] = *(const v4s*)&Bs[wn * 32 + ns * 16 + l15][ks * 32 + quad * 8];
          bb.h2[1] = *(const v4s*)&Bs[wn * 32 + ns * 16 + l15][ks * 32 + quad * 8 + 4];
          acc[ms][ns] = mfma16(a.v, bb.v, acc[ms][ns]);
        }
  }
#pragma unroll
  for (int ms = 0; ms < 2; ms++)
#pragma unroll
    for (int ns = 0; ns < 2; ns++) {
      int n = n0 + wn * 32 + ns * 16 + l15;
#pragma unroll
      for (int r = 0; r < 4; r++) {
        int m = m0 + wm * 32 + ms * 16 + quad * 4 + r;
        out[m * 512 + n] = acc[ms][ns][r];
      }
    }
}

// ---------------------------------------------------------------------------
extern "C" void kernel_launch(void* const* d_in, const int* in_sizes, int n_in,
                              void* d_out, int out_size, void* d_ws, size_t ws_size,
                              hipStream_t stream) {
  const float* q  = (const float*)d_in[0];
  const float* k  = (const float*)d_in[1];
  const float* v  = (const float*)d_in[2];
  const int* mask = (const int*)d_in[3];
  const float* Wq = (const float*)d_in[4];
  const float* Wo = (const float*)d_in[5];
  float* out = (float*)d_out;
  char* ws = (char*)d_ws;
  // ws: 0:QP 4MB | 4:KP | 8:VT | 16:MP 0.5MB | 16.5:Wob 0.5MB | 17:X 4MB
  short* QP = (short*)(ws);
  short* KP = (short*)(ws + (4u << 20));
  short* VT = (short*)(ws + (8u << 20));
  unsigned long long* MP = (unsigned long long*)(ws + (16u << 20));
  short* Wob = (short*)(ws + (16u << 20) + (512u << 10));
  short* X  = (short*)(ws + (17u << 20));

  proj_kernel<<<dim3(64, 8, 4), 256, 0, stream>>>(q, k, v, Wq, Wo, mask,
                                                  QP, KP, VT, Wob, MP);
  attn_kernel<<<dim3(32, N_H, 2), 512, 0, stream>>>(QP, KP, VT, MP, X);
  outproj_kernel<<<dim3(64, 8, 1), 256, 0, stream>>>(X, Wob, out);
}

// Round 7
// 139.172 us; speedup vs baseline: 1.1988x; 1.0646x over previous
//
#include <hip/hip_runtime.h>
#include <hip/hip_bf16.h>
#include <stdint.h>

// Problem: B=2, S=2048, D=512, H=8, DK=64
#define S_LEN 2048
#define D_MOD 512
#define N_H   8
#define D_K   64

typedef short v8s __attribute__((ext_vector_type(8)));
typedef short v4s __attribute__((ext_vector_type(4)));
typedef float v4f __attribute__((ext_vector_type(4)));

__device__ __forceinline__ short f2bf(float f) {        // RNE
  union { float f; unsigned u; } a; a.f = f;
  unsigned u = a.u;
  u += 0x7fffu + ((u >> 16) & 1u);
  return (short)(u >> 16);
}
__device__ __forceinline__ short f2bfh(float f) {       // round-half-up (p>=0)
  union { float f; unsigned u; } a; a.f = f;
  return (short)((a.u + 0x8000u) >> 16);
}
__device__ __forceinline__ float bf2f(short s) {        // exact
  union { unsigned u; float f; } x;
  x.u = ((unsigned)(unsigned short)s) << 16;
  return x.f;
}
// HW packed f32->bf16 (RNE), 2 values/instr
__device__ __forceinline__ unsigned pk2(float a, float b) {
  unsigned r;
  asm("v_cvt_pk_bf16_f32 %0, %1, %2" : "=v"(r) : "v"(a), "v"(b));
  return r;
}

__device__ __forceinline__ v4f mfma16(v8s a, v8s b, v4f c) {
  return __builtin_amdgcn_mfma_f32_16x16x32_bf16(a, b, c, 0, 0, 0);
}
__device__ __forceinline__ v4f mfma16x16(v4s a, v4s b, v4f c) {
  return __builtin_amdgcn_mfma_f32_16x16x16bf16_1k(a, b, c, 0, 0, 0);
}

// ---------------------------------------------------------------------------
// proj v2 (merged QKV): one block computes C_z = A_z @ Wq^T for ALL z in
// {q,k,v} on its 64x64 tile. Wq B-tile staged ONCE (was 3x: B was half of
// all staged bytes and a third of L2 load traffic), barriers amortized over
// 24 MFMAs/wave/K-step (was 8 — the v9->v10 density lever applied to proj).
// Fragment reads ordered ns->ks->B-load->ms->z: 28 b128/wave/K-step (was 48).
// z==1 plane keeps maskpack (bid<256) / Wo->bf16 aux work.
// ---------------------------------------------------------------------------
__global__ __launch_bounds__(256) void proj_kernel(
    const float* __restrict__ q, const float* __restrict__ k,
    const float* __restrict__ v, const float* __restrict__ Wq,
    const float* __restrict__ Wo, const int* __restrict__ mask,
    short* __restrict__ QP, short* __restrict__ KP, short* __restrict__ VT,
    short* __restrict__ Wob, unsigned long long* __restrict__ mp)
{
  const int tid = threadIdx.x;
  if (blockIdx.z == 1) {
    int bid = blockIdx.x * 8 + blockIdx.y;           // 0..511
    if (bid < 256) {                                  // maskpack
      int id = bid * 256 + tid;                       // 0..65535
      const int4* m4 = (const int4*)(mask + (size_t)id * 64);
      unsigned long long w = 0ull;
#pragma unroll
      for (int j = 0; j < 16; j++) {
        int4 mv = m4[j];
        w |= (unsigned long long)(mv.x != 0) << (j * 4 + 0);
        w |= (unsigned long long)(mv.y != 0) << (j * 4 + 1);
        w |= (unsigned long long)(mv.z != 0) << (j * 4 + 2);
        w |= (unsigned long long)(mv.w != 0) << (j * 4 + 3);
      }
      mp[id] = w;
    } else {                                          // Wo cvt
      unsigned off = (bid - 256) * 256 + tid;         // 0..65535
      float4 x = ((const float4*)Wo)[off];
      v4s p; p.x = f2bf(x.x); p.y = f2bf(x.y); p.z = f2bf(x.z); p.w = f2bf(x.w);
      ((v4s*)Wob)[off] = p;
    }
    return;
  }
  const int m0 = blockIdx.x * 64, n0 = blockIdx.y * 64;
  const int wave = tid >> 6, lane = tid & 63;
  const int quad = lane >> 4, l15 = lane & 15;
  const int wm = wave >> 1, wn = wave & 1;
  const float* Az[3] = {q, k, v};
  __shared__ short As[3][64][72];
  __shared__ short Bs[64][72];
  v4f acc[3][2][2];
#pragma unroll
  for (int z = 0; z < 3; z++)
#pragma unroll
    for (int i = 0; i < 2; i++)
#pragma unroll
      for (int j = 0; j < 2; j++) acc[z][i][j] = (v4f){0.f, 0.f, 0.f, 0.f};

  float4 a4[3][4], b4[4];
#pragma unroll
  for (int i = 0; i < 4; i++) {
    int fi = tid + i * 256, r = fi >> 4, c = (fi & 15) << 2;
#pragma unroll
    for (int z = 0; z < 3; z++)
      a4[z][i] = *(const float4*)&Az[z][(m0 + r) * 512 + c];
    b4[i] = *(const float4*)&Wq[(n0 + r) * 512 + c];
  }

  for (int kk = 0; kk < 512; kk += 64) {
    __syncthreads();
#pragma unroll
    for (int i = 0; i < 4; i++) {
      int fi = tid + i * 256, r = fi >> 4, c = (fi & 15) << 2;
#pragma unroll
      for (int z = 0; z < 3; z++) {
        union { unsigned u[2]; v4s s; } ap;
        ap.u[0] = pk2(a4[z][i].x, a4[z][i].y);
        ap.u[1] = pk2(a4[z][i].z, a4[z][i].w);
        *(v4s*)&As[z][r][c] = ap.s;
      }
      union { unsigned u[2]; v4s s; } bp;
      bp.u[0] = pk2(b4[i].x, b4[i].y);
      bp.u[1] = pk2(b4[i].z, b4[i].w);
      *(v4s*)&Bs[r][c] = bp.s;
    }
    __syncthreads();
    if (kk + 64 < 512) {
#pragma unroll
      for (int i = 0; i < 4; i++) {
        int fi = tid + i * 256, r = fi >> 4, c = (fi & 15) << 2;
#pragma unroll
        for (int z = 0; z < 3; z++)
          a4[z][i] = *(const float4*)&Az[z][(m0 + r) * 512 + kk + 64 + c];
        b4[i] = *(const float4*)&Wq[(n0 + r) * 512 + kk + 64 + c];
      }
    }
#pragma unroll
    for (int ns = 0; ns < 2; ns++)
#pragma unroll
      for (int ks = 0; ks < 2; ks++) {
        union { v8s v; v4s h2[2]; } bb;
        bb.h2[0] = *(const v4s*)&Bs[wn * 32 + ns * 16 + l15][ks * 32 + quad * 8];
        bb.h2[1] = *(const v4s*)&Bs[wn * 32 + ns * 16 + l15][ks * 32 + quad * 8 + 4];
#pragma unroll
        for (int ms = 0; ms < 2; ms++)
#pragma unroll
          for (int z = 0; z < 3; z++) {
            union { v8s v; v4s h2[2]; } a;
            a.h2[0] = *(const v4s*)&As[z][wm * 32 + ms * 16 + l15][ks * 32 + quad * 8];
            a.h2[1] = *(const v4s*)&As[z][wm * 32 + ms * 16 + l15][ks * 32 + quad * 8 + 4];
            acc[z][ms][ns] = mfma16(a.v, bb.v, acc[z][ms][ns]);
          }
      }
  }
#pragma unroll
  for (int z = 0; z < 3; z++)
#pragma unroll
    for (int ms = 0; ms < 2; ms++)
#pragma unroll
      for (int ns = 0; ns < 2; ns++) {
        int mb = m0 + wm * 32 + ms * 16 + quad * 4;
        int n  = n0 + wn * 32 + ns * 16 + l15;
        int bI = mb >> 11, s = mb & 2047, hh = n >> 6, dk = n & 63;
        if (z == 2) {
          v4s pv;
          pv.x = f2bf(acc[z][ms][ns][0]); pv.y = f2bf(acc[z][ms][ns][1]);
          pv.z = f2bf(acc[z][ms][ns][2]); pv.w = f2bf(acc[z][ms][ns][3]);
          *(v4s*)&VT[((bI * N_H + hh) * D_K + dk) * S_LEN + s] = pv;
        } else {
          short* dst = (z == 0) ? QP : KP;
#pragma unroll
          for (int r = 0; r < 4; r++)
            dst[((bI * N_H + hh) * S_LEN + (s + r)) * D_K + dk] = f2bf(acc[z][ms][ns][r]);
        }
      }
}

// ---------------------------------------------------------------------------
// Flash attention v11 (R6-proven): full-S blocks at 2 blocks/CU via
// KEY-PARITY wave split; in-block 2-way combine; writes FINAL bf16 X.
// ---------------------------------------------------------------------------
__global__ __launch_bounds__(512, 4) void attn_kernel(
    const short* __restrict__ QP, const short* __restrict__ KP,
    const short* __restrict__ VT, const unsigned long long* __restrict__ MP,
    short* __restrict__ X)
{
  const int qt = blockIdx.x;                 // 0..31 (64 q-rows each)
  const int h = blockIdx.y, b = blockIdx.z;
  const int tid = threadIdx.x;               // 0..511
  const int wave = tid >> 6, lane = tid & 63;
  const int quad = lane >> 4, l15 = lane & 15;
  const int qw = wave & 3, kg = wave >> 2;   // q-subtile, key-parity group
  const short* Qh = QP + ((b * N_H + h) * S_LEN) * D_K;
  const short* Kh = KP + ((b * N_H + h) * S_LEN) * D_K;
  const short* Vh = VT + ((b * N_H + h) * D_K) * S_LEN;

  __shared__ short SMEM[2][2][2][64][64];    // [pair][parity][K/V][row][col]

  const int qrow = qt * 64 + qw * 16;        // this wave's 16 q-rows
  const int srow = tid >> 3;                 // staging row 0..63
  const int sc8  = (tid & 7) * 8;            // staging col (shorts)
  const int scw  = sc8 ^ ((srow & 7) << 3);  // swizzled staging col
  const int swz  = (l15 & 7) << 3;           // read-side swizzle term

  v8s aQ[2];
#pragma unroll
  for (int ks = 0; ks < 2; ks++)
    aQ[ks] = *(const v8s*)&Qh[(qrow + l15) * D_K + ks * 32 + quad * 8];

  const float C1 = 0.18033688011112042f;     // 0.125 * log2(e)
  const float C2 = -11.541560327111707f;     // -8 * log2(e)
  const v4s ONES4 = {16256, 16256, 16256, 16256};
  v4f accX[4], accL = (v4f){0.f, 0.f, 0.f, 0.f};
#pragma unroll
  for (int u = 0; u < 4; u++) accX[u] = (v4f){0.f, 0.f, 0.f, 0.f};

  // prologue: stage tiles 0 (parity 0) and 1 (parity 1) into pair 0
  v8s kr0 = *(const v8s*)&Kh[srow * D_K + sc8];
  v8s vr0 = *(const v8s*)&Vh[srow * S_LEN + sc8];
  v8s kr1 = *(const v8s*)&Kh[(64 + srow) * D_K + sc8];
  v8s vr1 = *(const v8s*)&Vh[srow * S_LEN + 64 + sc8];
  *(v8s*)&SMEM[0][0][0][srow][scw] = kr0;
  *(v8s*)&SMEM[0][0][1][srow][scw] = vr0;
  *(v8s*)&SMEM[0][1][0][srow][scw] = kr1;
  *(v8s*)&SMEM[0][1][1][srow][scw] = vr1;
  unsigned long long mwc = MP[(qrow + l15) * 32 + kg];
  unsigned long long mwn = 0ull;
  __syncthreads();                           // pair 0 visible

  for (int it = 0; it < 16; it++) {
    const int p = it & 1;
    if (it + 1 < 16) {                       // prefetch next tile-PAIR to regs
      const int c0 = (it + 1) * 128, c1 = c0 + 64;
      kr0 = *(const v8s*)&Kh[(c0 + srow) * D_K + sc8];
      vr0 = *(const v8s*)&Vh[srow * S_LEN + c0 + sc8];
      kr1 = *(const v8s*)&Kh[(c1 + srow) * D_K + sc8];
      vr1 = *(const v8s*)&Vh[srow * S_LEN + c1 + sc8];
      mwn = MP[(qrow + l15) * 32 + 2 * (it + 1) + kg];
    }

    // this wave's tile = 2*it+kg, from SMEM[p][kg]
    v4s pa[4];
#pragma unroll
    for (int tp = 0; tp < 4; tp++) {
      v8s bK0 = *(const v8s*)&SMEM[p][kg][0][tp * 16 + l15][(quad * 8) ^ swz];
      v8s bK1 = *(const v8s*)&SMEM[p][kg][0][tp * 16 + l15][(32 + quad * 8) ^ swz];
      v4f s = mfma16(bK0, aQ[0], (v4f){0.f, 0.f, 0.f, 0.f});
      s = mfma16(bK1, aQ[1], s);
      unsigned mb = (unsigned)(mwc >> (tp * 16 + quad * 4));
      v4s pk;
#pragma unroll
      for (int r = 0; r < 4; r++) {
        float se = ((mb >> r) & 1u) ? s[r] : 0.0f;   // masked: exp2(C2)=e^-8
        float pr = __builtin_amdgcn_exp2f(fmaf(se, C1, C2));
        pk[r] = f2bfh(pr);
      }
      pa[tp] = pk;
    }

    // X += P @ V (register P); L += P @ 1 (row sums on MFMA pipe)
#pragma unroll
    for (int u = 0; u < 4; u++) {
      const short* vb_ = &SMEM[p][kg][1][u * 16 + l15][0];
#pragma unroll
      for (int tp = 0; tp < 4; tp++) {
        v4s bV = *(const v4s*)&vb_[(tp * 16 + quad * 4) ^ swz];
        accX[u] = mfma16x16(pa[tp], bV, accX[u]);
      }
    }
#pragma unroll
    for (int tp = 0; tp < 4; tp++)
      accL = mfma16x16(pa[tp], ONES4, accL);

    if (it + 1 < 16) {                       // write next pair
      *(v8s*)&SMEM[p ^ 1][0][0][srow][scw] = kr0;
      *(v8s*)&SMEM[p ^ 1][0][1][srow][scw] = vr0;
      *(v8s*)&SMEM[p ^ 1][1][0][srow][scw] = kr1;
      *(v8s*)&SMEM[p ^ 1][1][1][srow][scw] = vr1;
    }
    __syncthreads();
    mwc = mwn;
  }

  // 2-way combine across key-parity groups via LDS, normalize, write final X
  float* ex = (float*)&SMEM[0][0][0][0][0];  // 4 waves x 64 lanes x 21 floats
  const int xi = (qw * 64 + lane) * 21;      // stride 21: conflict-free
  if (kg == 1) {
#pragma unroll
    for (int u = 0; u < 4; u++)
#pragma unroll
      for (int r = 0; r < 4; r++) ex[xi + u * 4 + r] = accX[u][r];
#pragma unroll
    for (int r = 0; r < 4; r++) ex[xi + 16 + r] = accL[r];
  }
  __syncthreads();
  if (kg == 0) {
#pragma unroll
    for (int u = 0; u < 4; u++)
#pragma unroll
      for (int r = 0; r < 4; r++) accX[u][r] += ex[xi + u * 4 + r];
#pragma unroll
    for (int r = 0; r < 4; r++) accL[r] += ex[xi + 16 + r];
    v4f linv;
#pragma unroll
    for (int r = 0; r < 4; r++) linv[r] = 1.0f / accL[r];
#pragma unroll
    for (int u = 0; u < 4; u++)
#pragma unroll
      for (int r = 0; r < 4; r++) {
        int srw = qrow + quad * 4 + r;
        X[(b * S_LEN + srw) * D_MOD + h * D_K + u * 16 + l15] =
            f2bf(accX[u][r] * linv[r]);
      }
  }
}

// ---------------------------------------------------------------------------
// outproj (R4-proven clean): plain bf16 GEMM out = X @ Wo^T.
// ---------------------------------------------------------------------------
__global__ __launch_bounds__(256) void outproj_kernel(
    const short* __restrict__ X, const short* __restrict__ Wob,
    float* __restrict__ out)
{
  const int m0 = blockIdx.x * 64, n0 = blockIdx.y * 64;
  const int tid = threadIdx.x;
  const int wave = tid >> 6, lane = tid & 63;
  const int quad = lane >> 4, l15 = lane & 15;
  const int wm = wave >> 1, wn = wave & 1;
  __shared__ short As[64][72];
  __shared__ short Bs[64][72];

  v4f acc[2][2];
#pragma unroll
  for (int i = 0; i < 2; i++)
#pragma unroll
    for (int j = 0; j < 2; j++) acc[i][j] = (v4f){0.f, 0.f, 0.f, 0.f};

  v8s a8[2], b8[2];
#pragma unroll
  for (int i = 0; i < 2; i++) {
    int fi = tid + i * 256, r = fi >> 3, c = (fi & 7) << 3;
    a8[i] = *(const v8s*)&X[(m0 + r) * 512 + c];
    b8[i] = *(const v8s*)&Wob[(n0 + r) * 512 + c];
  }

  for (int kk = 0; kk < 512; kk += 64) {
    __syncthreads();
#pragma unroll
    for (int i = 0; i < 2; i++) {
      int fi = tid + i * 256, r = fi >> 3, c = (fi & 7) << 3;
      *(v8s*)&As[r][c] = a8[i];
      *(v8s*)&Bs[r][c] = b8[i];
    }
    __syncthreads();
    if (kk + 64 < 512) {
#pragma unroll
      for (int i = 0; i < 2; i++) {
        int fi = tid + i * 256, r = fi >> 3, c = (fi & 7) << 3;
        a8[i] = *(const v8s*)&X[(m0 + r) * 512 + kk + 64 + c];
        b8[i] = *(const v8s*)&Wob[(n0 + r) * 512 + kk + 64 + c];
      }
    }
#pragma unroll
    for (int ms = 0; ms < 2; ms++)
#pragma unroll
      for (int ns = 0; ns < 2; ns++)
#pragma unroll
        for (int ks = 0; ks < 2; ks++) {
          union { v8s v; v4s h2[2]; } a, bb;
          a.h2[0]  = *(const v4s*)&As[wm * 32 + ms * 16 + l15][ks * 32 + quad * 8];
          a.h2[1]  = *(const v4s*)&As[wm * 32 + ms * 16 + l15][ks * 32 + quad * 8 + 4];
          bb.h2[0] = *(const v4s*)&Bs[wn * 32 + ns * 16 + l15][ks * 32 + quad * 8];
          bb.h2[1] = *(const v4s*)&Bs[wn * 32 + ns * 16 + l15][ks * 32 + quad * 8 + 4];
          acc[ms][ns] = mfma16(a.v, bb.v, acc[ms][ns]);
        }
  }
#pragma unroll
  for (int ms = 0; ms < 2; ms++)
#pragma unroll
    for (int ns = 0; ns < 2; ns++) {
      int n = n0 + wn * 32 + ns * 16 + l15;
#pragma unroll
      for (int r = 0; r < 4; r++) {
        int m = m0 + wm * 32 + ms * 16 + quad * 4 + r;
        out[m * 512 + n] = acc[ms][ns][r];
      }
    }
}

// ---------------------------------------------------------------------------
extern "C" void kernel_launch(void* const* d_in, const int* in_sizes, int n_in,
                              void* d_out, int out_size, void* d_ws, size_t ws_size,
                              hipStream_t stream) {
  const float* q  = (const float*)d_in[0];
  const float* k  = (const float*)d_in[1];
  const float* v  = (const float*)d_in[2];
  const int* mask = (const int*)d_in[3];
  const float* Wq = (const float*)d_in[4];
  const float* Wo = (const float*)d_in[5];
  float* out = (float*)d_out;
  char* ws = (char*)d_ws;
  // ws: 0:QP 4MB | 4:KP | 8:VT | 16:MP 0.5MB | 16.5:Wob 0.5MB | 17:X 4MB
  short* QP = (short*)(ws);
  short* KP = (short*)(ws + (4u << 20));
  short* VT = (short*)(ws + (8u << 20));
  unsigned long long* MP = (unsigned long long*)(ws + (16u << 20));
  short* Wob = (short*)(ws + (16u << 20) + (512u << 10));
  short* X  = (short*)(ws + (17u << 20));

  proj_kernel<<<dim3(64, 8, 2), 256, 0, stream>>>(q, k, v, Wq, Wo, mask,
                                                  QP, KP, VT, Wob, MP);
  attn_kernel<<<dim3(32, N_H, 2), 512, 0, stream>>>(QP, KP, VT, MP, X);
  outproj_kernel<<<dim3(64, 8, 1), 256, 0, stream>>>(X, Wob, out);
}